// Round 4
// baseline (25464.723 us; speedup 1.0000x reference)
//
#include <hip/hip_runtime.h>
#include <math.h>

// Problem constants (from setup_inputs)
#define NSEQ 8192
#define DH 512
#define DZ 128
#define DE 128
#define VOCAB 64
#define TMAX 80
#define SOS 1
#define EOS_TOK 2

// GEMM tiling: 64 rows x (3 gates x 32 cols) per block, K-chunk 64, 4 waves (2x2).
// A (h-state) lives in registers (ping-pong prefetch); only B (weights) staged in LDS.
#define TMR 64
#define TNCOL 32

typedef _Float16 half_t;
typedef half_t h8 __attribute__((ext_vector_type(8)));
typedef float f4 __attribute__((ext_vector_type(4)));

__device__ __forceinline__ float sigf(float x) { return 1.0f / (1.0f + expf(-x)); }

// fp32 -> f16x2 split: v ~= hi + lo/2048, both RN. hi forced to 0 below f16
// min-normal so MFMA denorm behavior can't drop it (lo then carries v*2048,
// which is normal). Representation error <= 2^-22 |v|.
__device__ __forceinline__ void split2(float v, half_t& hi, half_t& lo) {
    float hf = (float)(half_t)v;
    if (fabsf(v) < 6.2e-5f) hf = 0.0f;
    hi = (half_t)hf;
    lo = (half_t)((v - hf) * 2048.0f);
}

__device__ __forceinline__ float rec2(half_t h, half_t l) {
    return (float)h + (float)l * (1.0f / 2048.0f);
}

__device__ __forceinline__ void gl_lds16(const void* g, void* l) {
    __builtin_amdgcn_global_load_lds((const __attribute__((address_space(1))) void*)g,
                                     (__attribute__((address_space(3))) void*)l, 16, 0, 0);
}

// XCD-aware swizzle: bid -> (row-tile 0..127, col-tile 0..15). Grid 2048.
__device__ __forceinline__ void swizzle_rc(int bid, int& r, int& c) {
    const int x = bid & 7;
    const int q = bid >> 3;       // 0..255
    r = (q & 15) * 8 + x;         // 0..127
    c = q >> 4;                   // 0..15
}

// ---------------------------------------------------------------- init
__global__ __launch_bounds__(256) void init_kernel(int* __restrict__ x_prev,
                                                   int* __restrict__ eos,
                                                   int* __restrict__ out,
                                                   int* __restrict__ list0,
                                                   int* __restrict__ counts) {
    int i = blockIdx.x * 256 + threadIdx.x;
    x_prev[i] = SOS;
    eos[i] = 0;
    list0[i] = i;
    out[i * TMAX] = SOS;
    out[NSEQ * TMAX + i] = TMAX;
    if (i < TMAX) counts[i] = (i == 0) ? NSEQ : 0;
}

// ---------------------------------------------------------------- h0 = Z @ z2h_w.T + b (fp64 acc) -> f16x2 splits x3 buffers
__global__ __launch_bounds__(256) void h0_kernel(const float* __restrict__ Z,
                                                 const float* __restrict__ w,
                                                 const float* __restrict__ b,
                                                 half_t* __restrict__ B0h, half_t* __restrict__ B0l,
                                                 half_t* __restrict__ B1h, half_t* __restrict__ B1l,
                                                 half_t* __restrict__ B2h, half_t* __restrict__ B2l) {
    __shared__ float zrow[DZ];
    const int i = blockIdx.x;
    const int tid = threadIdx.x;
    if (tid < DZ) zrow[tid] = Z[(size_t)i * DZ + tid];
    __syncthreads();
    for (int j = tid; j < DH; j += 256) {
        double s = (double)b[j];
        const float* wr = w + (size_t)j * DZ;
#pragma unroll 8
        for (int k = 0; k < DZ; ++k) s += (double)zrow[k] * (double)wr[k];
        float sf = (float)s;
        half_t hi, lo;
        split2(sf, hi, lo);
        size_t o = (size_t)i * DH + j;
        B0h[o] = hi; B0l[o] = lo;
        B1h[o] = hi; B1l[o] = lo;
        B2h[o] = hi; B2l[o] = lo;
    }
}

// ---------------------------------------------------------------- gi0 table (fp64)
__global__ __launch_bounds__(256) void gi0_kernel(const float* __restrict__ emb,
                                                  const float* __restrict__ w_ih0,
                                                  const float* __restrict__ b_ih0,
                                                  double* __restrict__ tab) {
    __shared__ float e[DE];
    const int x = blockIdx.x;
    const int tid = threadIdx.x;
    if (tid < DE) e[tid] = emb[(size_t)x * DE + tid];
    __syncthreads();
    for (int j = tid; j < 3 * DH; j += 256) {
        double s = (double)b_ih0[j];
        const float* wr = w_ih0 + (size_t)j * DE;
#pragma unroll 8
        for (int k = 0; k < DE; ++k) s += (double)e[k] * (double)wr[k];
        tab[(size_t)x * 3 * DH + j] = s;
    }
}

// ---------------------------------------------------------------- weight split fp32 -> f16 hi/lo
__global__ __launch_bounds__(256) void wsplit_kernel(const float* __restrict__ w,
                                                     half_t* __restrict__ hi,
                                                     half_t* __restrict__ lo, int n) {
    int i = blockIdx.x * 256 + threadIdx.x;
    if (i < n) {
        half_t h, l;
        split2(w[i], h, l);
        hi[i] = h; lo[i] = l;
    }
}

// LDS: B only, double-buffered. Per buffer 24576 B: [0,12288) B_hi (96 rows x
// 8 slots x 16B), [12288,24576) B_lo. Row r slot s holds global k-slot
// (s ^ (r&7)) (16B XOR swizzle on the GLOBAL source so global_load_lds dests
// stay linear). Buffers at 0 and 24576 (total 48 KB -> 3 blocks/CU).

// ---------------------------------------------------------------- layer 0: f16x2 emulated-fp32 MFMA, A-in-reg, B dbuf, counted vmcnt
__global__ __launch_bounds__(256, 3) void layer0_mfma(
    const half_t* __restrict__ Hch, const half_t* __restrict__ Hcl,
    half_t* __restrict__ Hnh, half_t* __restrict__ Hnl,
    const half_t* __restrict__ Wh, const half_t* __restrict__ Wl,
    const float* __restrict__ b_hh0,
    const double* __restrict__ tab,
    const int* __restrict__ x_prev,
    const int* __restrict__ list, const int* __restrict__ count) {
    int rt, ct;
    swizzle_rc(blockIdx.x, rt, ct);
    const int row0 = rt * TMR;
    const int cnt = count[0];
    if (row0 >= cnt) return;
    const int col0 = ct * TNCOL;

    __shared__ __align__(16) char sm[49152];
    const int tid = threadIdx.x;
    const int lane = tid & 63, w = tid >> 6;
    const int lr = lane & 15, lq = lane >> 4;
    const int wr0 = (w >> 1) * 32, wc0 = (w & 1) * 16;

    // B staging offsets (chunk-invariant; add kc*128 per chunk). 6 gl_lds/thread.
    unsigned bsrc[3]; int bldsu[3];
#pragma unroll
    for (int j = 0; j < 3; ++j) {
        int u = j * 256 + tid, br = u >> 3, s = u & 7;
        bsrc[j] = (unsigned)(((br >> 5) * DH + col0 + (br & 31)) * 1024 + ((s ^ (br & 7)) << 4));
        bldsu[j] = u * 16;
    }
    // B fragment LDS offsets
    int fb[3][2];
#pragma unroll
    for (int g = 0; g < 3; ++g)
#pragma unroll
        for (int ks = 0; ks < 2; ++ks) {
            int br = g * 32 + wc0 + lr;
            fb[g][ks] = br * 128 + (((ks * 4 + lq) ^ (br & 7)) << 4);
        }
    // A register-load bases (row clamped to cnt-1; pad rows duplicate last row,
    // so their outputs are value-identical duplicates of row cnt-1)
    unsigned abase[2];
#pragma unroll
    for (int rf = 0; rf < 2; ++rf) {
        int ri = row0 + wr0 + rf * 16 + lr;
        if (ri > cnt - 1) ri = cnt - 1;
        abase[rf] = (unsigned)list[ri] * 1024u + (unsigned)(lq * 16);
    }

    f4 hh[2][3] = {}, cc[2][3] = {};

    auto stageB = [&](int bb, int kc) {
        const unsigned ko = (unsigned)kc * 128u;
#pragma unroll
        for (int j = 0; j < 3; ++j) {
            gl_lds16((const char*)Wh + (size_t)(bsrc[j] + ko), sm + bb + bldsu[j]);
            gl_lds16((const char*)Wl + (size_t)(bsrc[j] + ko), sm + bb + 12288 + bldsu[j]);
        }
    };
    auto loadA = [&](h8* d, int kc) {
        const unsigned ko = (unsigned)kc * 128u;
#pragma unroll
        for (int rf = 0; rf < 2; ++rf)
#pragma unroll
            for (int ks = 0; ks < 2; ++ks) {
                const size_t off = (size_t)(abase[rf] + ko + (unsigned)(ks * 64));
                d[rf * 4 + ks * 2 + 0] = *(const h8*)((const char*)Hch + off);
                d[rf * 4 + ks * 2 + 1] = *(const h8*)((const char*)Hcl + off);
            }
    };
    auto compute = [&](int bb, const h8* A) {
#pragma unroll
        for (int ks = 0; ks < 2; ++ks)
#pragma unroll
            for (int g = 0; g < 3; ++g) {
                h8 bh = *(const h8*)(sm + bb + fb[g][ks]);
                h8 bl = *(const h8*)(sm + bb + 12288 + fb[g][ks]);
#pragma unroll
                for (int rf = 0; rf < 2; ++rf) {
                    hh[rf][g] = __builtin_amdgcn_mfma_f32_16x16x32_f16(A[rf * 4 + ks * 2], bh, hh[rf][g], 0, 0, 0);
                    cc[rf][g] = __builtin_amdgcn_mfma_f32_16x16x32_f16(A[rf * 4 + ks * 2], bl, cc[rf][g], 0, 0, 0);
                    cc[rf][g] = __builtin_amdgcn_mfma_f32_16x16x32_f16(A[rf * 4 + ks * 2 + 1], bh, cc[rf][g], 0, 0, 0);
                }
            }
    };

    // K = 512 = 8 chunks of 64. Two chunks per iteration (ping-pong).
    h8 A0[8], A1[8];
    stageB(0, 0); loadA(A0, 0);                       // 14 VMEM
    for (int kc = 0; kc < 8; kc += 2) {
        stageB(24576, kc + 1); loadA(A1, kc + 1);     // 14 VMEM
        asm volatile("s_waitcnt vmcnt(14)" ::: "memory");
        asm volatile("s_barrier" ::: "memory");
        compute(0, A0);
        asm volatile("s_waitcnt lgkmcnt(0)" ::: "memory");
        asm volatile("s_barrier" ::: "memory");
        if (kc + 2 < 8) {
            stageB(0, kc + 2); loadA(A0, kc + 2);
            asm volatile("s_waitcnt vmcnt(14)" ::: "memory");
        } else {
            asm volatile("s_waitcnt vmcnt(0)" ::: "memory");
        }
        asm volatile("s_barrier" ::: "memory");
        compute(24576, A1);
        asm volatile("s_waitcnt lgkmcnt(0)" ::: "memory");
        asm volatile("s_barrier" ::: "memory");
    }

    const int colg = col0 + wc0 + lr;
    const float inv = 1.0f / 2048.0f;
#pragma unroll
    for (int rf = 0; rf < 2; ++rf) {
        f4 pR = hh[rf][0] + cc[rf][0] * inv;
        f4 pZ = hh[rf][1] + cc[rf][1] * inv;
        f4 pN = hh[rf][2] + cc[rf][2] * inv;
#pragma unroll
        for (int reg = 0; reg < 4; ++reg) {
            int ri = row0 + wr0 + rf * 16 + lq * 4 + reg;
            if (ri > cnt - 1) ri = cnt - 1;
            const int gi = list[ri];
            const double* tr = tab + (size_t)x_prev[gi] * (3 * DH);
            float xr = (float)(tr[colg] + (double)pR[reg] + (double)b_hh0[colg]);
            float xz = (float)(tr[DH + colg] + (double)pZ[reg] + (double)b_hh0[DH + colg]);
            float hn_pre = pN[reg] + b_hh0[2 * DH + colg];
            float rg = sigf(xr), zg = sigf(xz);
            float gg = tanhf((float)(tr[2 * DH + colg] + (double)rg * (double)hn_pre));
            size_t o = (size_t)gi * DH + colg;
            float ho = rec2(Hch[o], Hcl[o]);
            float hv = (1.0f - zg) * gg + zg * ho;
            half_t oh, ol;
            split2(hv, oh, ol);
            Hnh[o] = oh; Hnl[o] = ol;
        }
    }
}

// ---------------------------------------------------------------- layers 1/2: fused K=1024 (x-half chunks 0..7, h-half 8..15)
__global__ __launch_bounds__(256, 3) void layer12_mfma(
    const half_t* __restrict__ Xh, const half_t* __restrict__ Xl,
    const half_t* __restrict__ Hch, const half_t* __restrict__ Hcl,
    half_t* __restrict__ Hnh, half_t* __restrict__ Hnl,
    const half_t* __restrict__ Wih_h, const half_t* __restrict__ Wih_l,
    const half_t* __restrict__ Whh_h, const half_t* __restrict__ Whh_l,
    const float* __restrict__ b_ih, const float* __restrict__ b_hh,
    const int* __restrict__ list, const int* __restrict__ count) {
    int rt, ct;
    swizzle_rc(blockIdx.x, rt, ct);
    const int row0 = rt * TMR;
    const int cnt = count[0];
    if (row0 >= cnt) return;
    const int col0 = ct * TNCOL;

    __shared__ __align__(16) char sm[49152];
    const int tid = threadIdx.x;
    const int lane = tid & 63, w = tid >> 6;
    const int lr = lane & 15, lq = lane >> 4;
    const int wr0 = (w >> 1) * 32, wc0 = (w & 1) * 16;

    unsigned bsrc[3]; int bldsu[3];
#pragma unroll
    for (int j = 0; j < 3; ++j) {
        int u = j * 256 + tid, br = u >> 3, s = u & 7;
        bsrc[j] = (unsigned)(((br >> 5) * DH + col0 + (br & 31)) * 1024 + ((s ^ (br & 7)) << 4));
        bldsu[j] = u * 16;
    }
    int fb[3][2];
#pragma unroll
    for (int g = 0; g < 3; ++g)
#pragma unroll
        for (int ks = 0; ks < 2; ++ks) {
            int br = g * 32 + wc0 + lr;
            fb[g][ks] = br * 128 + (((ks * 4 + lq) ^ (br & 7)) << 4);
        }
    unsigned abase[2];
#pragma unroll
    for (int rf = 0; rf < 2; ++rf) {
        int ri = row0 + wr0 + rf * 16 + lr;
        if (ri > cnt - 1) ri = cnt - 1;
        abase[rf] = (unsigned)list[ri] * 1024u + (unsigned)(lq * 16);
    }

    f4 hh[2][3] = {}, cc[2][3] = {}, niS[2] = {};

    auto stageB = [&](int bb, int kc) {
        const half_t* Bh_ = (kc < 8) ? Wih_h : Whh_h;
        const half_t* Bl_ = (kc < 8) ? Wih_l : Whh_l;
        const unsigned ko = (unsigned)(kc & 7) * 128u;
#pragma unroll
        for (int j = 0; j < 3; ++j) {
            gl_lds16((const char*)Bh_ + (size_t)(bsrc[j] + ko), sm + bb + bldsu[j]);
            gl_lds16((const char*)Bl_ + (size_t)(bsrc[j] + ko), sm + bb + 12288 + bldsu[j]);
        }
    };
    auto loadA = [&](h8* d, int kc) {
        const char* Ah_ = (kc < 8) ? (const char*)Xh : (const char*)Hch;
        const char* Al_ = (kc < 8) ? (const char*)Xl : (const char*)Hcl;
        const unsigned ko = (unsigned)(kc & 7) * 128u;
#pragma unroll
        for (int rf = 0; rf < 2; ++rf)
#pragma unroll
            for (int ks = 0; ks < 2; ++ks) {
                const size_t off = (size_t)(abase[rf] + ko + (unsigned)(ks * 64));
                d[rf * 4 + ks * 2 + 0] = *(const h8*)(Ah_ + off);
                d[rf * 4 + ks * 2 + 1] = *(const h8*)(Al_ + off);
            }
    };
    auto compute = [&](int bb, const h8* A) {
#pragma unroll
        for (int ks = 0; ks < 2; ++ks)
#pragma unroll
            for (int g = 0; g < 3; ++g) {
                h8 bh = *(const h8*)(sm + bb + fb[g][ks]);
                h8 bl = *(const h8*)(sm + bb + 12288 + fb[g][ks]);
#pragma unroll
                for (int rf = 0; rf < 2; ++rf) {
                    hh[rf][g] = __builtin_amdgcn_mfma_f32_16x16x32_f16(A[rf * 4 + ks * 2], bh, hh[rf][g], 0, 0, 0);
                    cc[rf][g] = __builtin_amdgcn_mfma_f32_16x16x32_f16(A[rf * 4 + ks * 2], bl, cc[rf][g], 0, 0, 0);
                    cc[rf][g] = __builtin_amdgcn_mfma_f32_16x16x32_f16(A[rf * 4 + ks * 2 + 1], bh, cc[rf][g], 0, 0, 0);
                }
            }
    };

    // 16 chunks of 64: chunks 0..7 = x @ w_ih, chunks 8..15 = h @ w_hh.
    h8 A0[8], A1[8];
    stageB(0, 0); loadA(A0, 0);
    for (int kc = 0; kc < 16; kc += 2) {
        stageB(24576, kc + 1); loadA(A1, kc + 1);
        asm volatile("s_waitcnt vmcnt(14)" ::: "memory");
        asm volatile("s_barrier" ::: "memory");
        compute(0, A0);
        asm volatile("s_waitcnt lgkmcnt(0)" ::: "memory");
        asm volatile("s_barrier" ::: "memory");
        if (kc + 2 < 16) {
            stageB(0, kc + 2); loadA(A0, kc + 2);
            asm volatile("s_waitcnt vmcnt(14)" ::: "memory");
        } else {
            asm volatile("s_waitcnt vmcnt(0)" ::: "memory");
        }
        asm volatile("s_barrier" ::: "memory");
        compute(24576, A1);
        if (kc == 6) {
            // chunk 7 just computed = end of x-half: save i_n partial, reset n-gate accums
#pragma unroll
            for (int rf = 0; rf < 2; ++rf) {
                niS[rf] = hh[rf][2] + cc[rf][2] * (1.0f / 2048.0f);
                f4 zz = {0.0f, 0.0f, 0.0f, 0.0f};
                hh[rf][2] = zz; cc[rf][2] = zz;
            }
        }
        asm volatile("s_waitcnt lgkmcnt(0)" ::: "memory");
        asm volatile("s_barrier" ::: "memory");
    }

    const int colg = col0 + wc0 + lr;
    const float inv = 1.0f / 2048.0f;
#pragma unroll
    for (int rf = 0; rf < 2; ++rf) {
        f4 pR = hh[rf][0] + cc[rf][0] * inv;
        f4 pZ = hh[rf][1] + cc[rf][1] * inv;
        f4 pNH = hh[rf][2] + cc[rf][2] * inv;
#pragma unroll
        for (int reg = 0; reg < 4; ++reg) {
            int ri = row0 + wr0 + rf * 16 + lq * 4 + reg;
            if (ri > cnt - 1) ri = cnt - 1;
            const int gi = list[ri];
            float xr = pR[reg] + b_ih[colg] + b_hh[colg];
            float xz = pZ[reg] + b_ih[DH + colg] + b_hh[DH + colg];
            float xi = niS[rf][reg] + b_ih[2 * DH + colg];
            float hn_pre = pNH[reg] + b_hh[2 * DH + colg];
            float rg = sigf(xr), zg = sigf(xz);
            float gg = tanhf(xi + rg * hn_pre);
            size_t o = (size_t)gi * DH + colg;
            float ho = rec2(Hch[o], Hcl[o]);
            float hv = (1.0f - zg) * gg + zg * ho;
            half_t oh, ol;
            split2(hv, oh, ol);
            Hnh[o] = oh; Hnl[o] = ol;
        }
    }
}

// ---------------------------------------------------------------- logits + softmax + argmax + token update + fused compaction
__global__ __launch_bounds__(256) void logits_kernel(const half_t* __restrict__ H2h,
                                                     const half_t* __restrict__ H2l,
                                                     const float* __restrict__ h2v_w,
                                                     const float* __restrict__ h2v_b,
                                                     int* __restrict__ x_prev,
                                                     int* __restrict__ eos,
                                                     int* __restrict__ out,
                                                     const int* __restrict__ list,
                                                     const int* __restrict__ count,
                                                     int* __restrict__ list_next,
                                                     int* __restrict__ count_next,
                                                     int t) {
    const int rowbase = blockIdx.x * 16;
    const int cnt = count[0];
    if (rowbase >= cnt) return;

    __shared__ float Ws[VOCAB][65];
    __shared__ float Hs[16][65];
    __shared__ int sact[16];
    const int tid = threadIdx.x;
    double acc[4] = {0.0, 0.0, 0.0, 0.0};

    for (int k0 = 0; k0 < DH; k0 += 64) {
        __syncthreads();
#pragma unroll
        for (int it = 0; it < 16; ++it) {
            int idx = tid + 256 * it;
            int v = idx >> 6, k = idx & 63;
            Ws[v][k] = h2v_w[(size_t)v * DH + k0 + k];
        }
#pragma unroll
        for (int it = 0; it < 4; ++it) {
            int idx = tid + 256 * it;
            int r = idx >> 6, k = idx & 63;
            int pos = rowbase + r; if (pos > cnt - 1) pos = cnt - 1;
            size_t o = (size_t)list[pos] * DH + k0 + k;
            Hs[r][k] = rec2(H2h[o], H2l[o]);
        }
        __syncthreads();
        const int r = tid >> 4;
        const int vb = (tid & 15) * 4;
#pragma unroll 16
        for (int k = 0; k < 64; ++k) {
            double h = (double)Hs[r][k];
            acc[0] += h * (double)Ws[vb + 0][k];
            acc[1] += h * (double)Ws[vb + 1][k];
            acc[2] += h * (double)Ws[vb + 2][k];
            acc[3] += h * (double)Ws[vb + 3][k];
        }
    }

    const int r = tid >> 4;
    const int vb = (tid & 15) * 4;
    float lf[4];
#pragma unroll
    for (int vv = 0; vv < 4; ++vv) lf[vv] = (float)(acc[vv] + (double)h2v_b[vb + vv]);

    float m = fmaxf(fmaxf(lf[0], lf[1]), fmaxf(lf[2], lf[3]));
#pragma unroll
    for (int off = 1; off < 16; off <<= 1) m = fmaxf(m, __shfl_xor(m, off));
    float e[4];
    float ssum = 0.f;
#pragma unroll
    for (int vv = 0; vv < 4; ++vv) { e[vv] = expf(lf[vv] - m); ssum += e[vv]; }
#pragma unroll
    for (int off = 1; off < 16; off <<= 1) ssum += __shfl_xor(ssum, off);

    float best = e[0] / ssum;
    int bi = vb;
#pragma unroll
    for (int vv = 1; vv < 4; ++vv) {
        float pv = e[vv] / ssum;
        if (pv > best) { best = pv; bi = vb + vv; }
    }
#pragma unroll
    for (int off = 1; off < 16; off <<= 1) {
        float ov = __shfl_xor(best, off);
        int oi = __shfl_xor(bi, off);
        if (ov > best || (ov == best && oi < bi)) { best = ov; bi = oi; }
    }
    if ((tid & 15) == 0) {
        const int pos = rowbase + r;
        const bool valid = pos < cnt;
        const int gi = list[valid ? pos : (cnt - 1)];
        const int ee = eos[gi];
        const int xt = bi;
        if (valid) {
            out[(size_t)gi * TMAX + t] = ee ? 0 : xt;
            if (!ee && xt == EOS_TOK) {
                out[NSEQ * TMAX + gi] = t + 1;
                eos[gi] = 1;
            }
            x_prev[gi] = xt;
        }
        sact[r] = (valid && !ee && xt != EOS_TOK) ? gi : -1;
    }
    __syncthreads();
    if (tid == 0) {
        int loc[16], k = 0;
#pragma unroll
        for (int i = 0; i < 16; ++i) { int v = sact[i]; if (v >= 0) loc[k++] = v; }
        if (k > 0) {
            int b = atomicAdd(count_next, k);
            for (int i = 0; i < k; ++i) list_next[b + i] = loc[i];
        }
    }
}

// ---------------------------------------------------------------- host
extern "C" void kernel_launch(void* const* d_in, const int* in_sizes, int n_in,
                              void* d_out, int out_size, void* d_ws, size_t ws_size,
                              hipStream_t stream) {
    const float* Z        = (const float*)d_in[0];
    const float* emb      = (const float*)d_in[1];
    const float* z2h_w    = (const float*)d_in[2];
    const float* z2h_b    = (const float*)d_in[3];
    const float* w_ih0    = (const float*)d_in[4];
    const float* w_ih_rest= (const float*)d_in[5];   // [2][1536][512]
    const float* w_hh     = (const float*)d_in[6];   // [3][1536][512]
    const float* b_ih     = (const float*)d_in[7];   // [3][1536]
    const float* b_hh     = (const float*)d_in[8];
    const float* h2v_w    = (const float*)d_in[9];
    const float* h2v_b    = (const float*)d_in[10];

    int* out = (int*)d_out;
    char* p = (char*)d_ws;
    const size_t HS = (size_t)NSEQ * DH * sizeof(half_t);   // 8 MiB per split buffer
    half_t* Bh[4]; half_t* Bl[4];
    for (int i = 0; i < 4; ++i) { Bh[i] = (half_t*)p; p += HS; }
    for (int i = 0; i < 4; ++i) { Bl[i] = (half_t*)p; p += HS; }
    double* tab = (double*)p; p += (size_t)VOCAB * 3 * DH * sizeof(double);
    const size_t WH = (size_t)3 * DH * DH;   // elems per weight matrix (1536*512)
    half_t* wih_h = (half_t*)p; p += 2 * WH * sizeof(half_t);
    half_t* wih_l = (half_t*)p; p += 2 * WH * sizeof(half_t);
    half_t* whh_h = (half_t*)p; p += 3 * WH * sizeof(half_t);
    half_t* whh_l = (half_t*)p; p += 3 * WH * sizeof(half_t);
    int* x_prev = (int*)p; p += NSEQ * sizeof(int);
    int* eos    = (int*)p; p += NSEQ * sizeof(int);
    int* lists[2];
    lists[0] = (int*)p; p += NSEQ * sizeof(int);
    lists[1] = (int*)p; p += NSEQ * sizeof(int);
    int* counts = (int*)p; p += 128 * sizeof(int);

    // PAD-fill token region so skipped (post-EOS) rows read as PAD=0.
    hipMemsetAsync(out, 0, (size_t)NSEQ * TMAX * sizeof(int), stream);
    init_kernel<<<NSEQ / 256, 256, 0, stream>>>(x_prev, eos, out, lists[0], counts);
    h0_kernel<<<NSEQ, 256, 0, stream>>>(Z, z2h_w, z2h_b,
                                        Bh[0], Bl[0], Bh[1], Bl[1], Bh[2], Bl[2]);
    gi0_kernel<<<VOCAB, 256, 0, stream>>>(emb, w_ih0, b_ih, tab);
    wsplit_kernel<<<(int)((2 * WH + 255) / 256), 256, 0, stream>>>(w_ih_rest, wih_h, wih_l, (int)(2 * WH));
    wsplit_kernel<<<(int)((3 * WH + 255) / 256), 256, 0, stream>>>(w_hh, whh_h, whh_l, (int)(3 * WH));

    int c0 = 0, c1 = 1, c2 = 2, sp = 3;
    const int lgrid = (NSEQ / TMR) * (DH / TNCOL);   // 128*16 = 2048, 1-D swizzled
    for (int t = 1; t < TMAX; ++t) {
        const int* lcur = lists[(t - 1) & 1];
        const int* ccur = counts + (t - 1);
        layer0_mfma<<<lgrid, 256, 0, stream>>>(Bh[c0], Bl[c0], Bh[sp], Bl[sp],
            whh_h, whh_l, b_hh, tab, x_prev, lcur, ccur);
        layer12_mfma<<<lgrid, 256, 0, stream>>>(Bh[sp], Bl[sp], Bh[c1], Bl[c1], Bh[c0], Bl[c0],
            wih_h, wih_l, whh_h + WH, whh_l + WH, b_ih + 3 * DH, b_hh + 3 * DH, lcur, ccur);
        layer12_mfma<<<lgrid, 256, 0, stream>>>(Bh[c0], Bl[c0], Bh[c2], Bl[c2], Bh[c1], Bl[c1],
            wih_h + WH, wih_l + WH, whh_h + 2 * WH, whh_l + 2 * WH,
            b_ih + 6 * DH, b_hh + 6 * DH, lcur, ccur);
        logits_kernel<<<NSEQ / 16, 256, 0, stream>>>(Bh[c1], Bl[c1], h2v_w, h2v_b,
                                                     x_prev, eos, out, lcur, ccur,
                                                     lists[t & 1], counts + t, t);
        int n0 = sp, n1 = c0, n2 = c1, nsp = c2;
        c0 = n0; c1 = n1; c2 = n2; sp = nsp;
    }
}

// Round 5
// 14756.584 us; speedup vs baseline: 1.7257x; 1.7257x over previous
//
#include <hip/hip_runtime.h>
#include <math.h>

// Problem constants (from setup_inputs)
#define NSEQ 8192
#define DH 512
#define DZ 128
#define DE 128
#define VOCAB 64
#define TMAX 80
#define SOS 1
#define EOS_TOK 2

// GEMM tiling: 64 rows x (3 gates x 32 cols) per block, K-chunk 64, 4 waves (2x2).
#define TMR 64
#define TNCOL 32

typedef _Float16 half_t;
typedef half_t h8 __attribute__((ext_vector_type(8)));
typedef float f4 __attribute__((ext_vector_type(4)));

__device__ __forceinline__ float sigf(float x) { return 1.0f / (1.0f + expf(-x)); }

// fp32 -> f16x2 split: v ~= hi + lo/2048, both RN. hi forced to 0 below f16
// min-normal so MFMA denorm behavior can't drop it (lo then carries v*2048,
// which is normal). Representation error <= 2^-22 |v|.
__device__ __forceinline__ void split2(float v, half_t& hi, half_t& lo) {
    float hf = (float)(half_t)v;
    if (fabsf(v) < 6.2e-5f) hf = 0.0f;
    hi = (half_t)hf;
    lo = (half_t)((v - hf) * 2048.0f);
}

__device__ __forceinline__ float rec2(half_t h, half_t l) {
    return (float)h + (float)l * (1.0f / 2048.0f);
}

__device__ __forceinline__ void gl_lds16(const void* g, void* l) {
    __builtin_amdgcn_global_load_lds((const __attribute__((address_space(1))) void*)g,
                                     (__attribute__((address_space(3))) void*)l, 16, 0, 0);
}

// XCD-aware swizzle: bid -> (row-tile 0..127, col-tile 0..15). Grid 2048.
__device__ __forceinline__ void swizzle_rc(int bid, int& r, int& c) {
    const int x = bid & 7;
    const int q = bid >> 3;       // 0..255
    r = (q & 15) * 8 + x;         // 0..127
    c = q >> 4;                   // 0..15
}

// ---------------------------------------------------------------- init
__global__ __launch_bounds__(256) void init_kernel(int* __restrict__ x_prev,
                                                   int* __restrict__ eos,
                                                   int* __restrict__ out,
                                                   int* __restrict__ list0,
                                                   int* __restrict__ counts) {
    int i = blockIdx.x * 256 + threadIdx.x;
    x_prev[i] = SOS;
    eos[i] = 0;
    list0[i] = i;
    out[i * TMAX] = SOS;
    out[NSEQ * TMAX + i] = TMAX;
    if (i < TMAX) counts[i] = (i == 0) ? NSEQ : 0;
}

// ---------------------------------------------------------------- h0 = Z @ z2h_w.T + b (fp64 acc) -> f16x2 splits x3 buffers
__global__ __launch_bounds__(256) void h0_kernel(const float* __restrict__ Z,
                                                 const float* __restrict__ w,
                                                 const float* __restrict__ b,
                                                 half_t* __restrict__ B0h, half_t* __restrict__ B0l,
                                                 half_t* __restrict__ B1h, half_t* __restrict__ B1l,
                                                 half_t* __restrict__ B2h, half_t* __restrict__ B2l) {
    __shared__ float zrow[DZ];
    const int i = blockIdx.x;
    const int tid = threadIdx.x;
    if (tid < DZ) zrow[tid] = Z[(size_t)i * DZ + tid];
    __syncthreads();
    for (int j = tid; j < DH; j += 256) {
        double s = (double)b[j];
        const float* wr = w + (size_t)j * DZ;
#pragma unroll 8
        for (int k = 0; k < DZ; ++k) s += (double)zrow[k] * (double)wr[k];
        float sf = (float)s;
        half_t hi, lo;
        split2(sf, hi, lo);
        size_t o = (size_t)i * DH + j;
        B0h[o] = hi; B0l[o] = lo;
        B1h[o] = hi; B1l[o] = lo;
        B2h[o] = hi; B2l[o] = lo;
    }
}

// ---------------------------------------------------------------- gi0 table (fp64)
__global__ __launch_bounds__(256) void gi0_kernel(const float* __restrict__ emb,
                                                  const float* __restrict__ w_ih0,
                                                  const float* __restrict__ b_ih0,
                                                  double* __restrict__ tab) {
    __shared__ float e[DE];
    const int x = blockIdx.x;
    const int tid = threadIdx.x;
    if (tid < DE) e[tid] = emb[(size_t)x * DE + tid];
    __syncthreads();
    for (int j = tid; j < 3 * DH; j += 256) {
        double s = (double)b_ih0[j];
        const float* wr = w_ih0 + (size_t)j * DE;
#pragma unroll 8
        for (int k = 0; k < DE; ++k) s += (double)e[k] * (double)wr[k];
        tab[(size_t)x * 3 * DH + j] = s;
    }
}

// ---------------------------------------------------------------- weight split fp32 -> f16 hi/lo
__global__ __launch_bounds__(256) void wsplit_kernel(const float* __restrict__ w,
                                                     half_t* __restrict__ hi,
                                                     half_t* __restrict__ lo, int n) {
    int i = blockIdx.x * 256 + threadIdx.x;
    if (i < n) {
        half_t h, l;
        split2(w[i], h, l);
        hi[i] = h; lo[i] = l;
    }
}

// LDS layout (bytes): [0,8192) A_hi [64][64]f16, [8192,16384) A_lo,
// [16384,28672) B_hi [96][64]f16, [28672,40960) B_lo. Element (r,k) stored at
// r*128 + ((k>>3) ^ (r&7))*16 + (k&7)*2  (16B-slot XOR swizzle; the swizzle is
// applied on the GLOBAL source address so global_load_lds writes stay linear).

// ---------------------------------------------------------------- layer 0: f16x2 emulated-fp32 MFMA GEMM
__global__ __launch_bounds__(256, 3) void layer0_mfma(
    const half_t* __restrict__ Hch, const half_t* __restrict__ Hcl,
    half_t* __restrict__ Hnh, half_t* __restrict__ Hnl,
    const half_t* __restrict__ Wh, const half_t* __restrict__ Wl,
    const float* __restrict__ b_hh0,
    const double* __restrict__ tab,
    const int* __restrict__ x_prev,
    const int* __restrict__ list, const int* __restrict__ count) {
    int rt, ct;
    swizzle_rc(blockIdx.x, rt, ct);
    const int row0 = rt * TMR;
    const int cnt = count[0];
    if (row0 >= cnt) return;
    const int col0 = ct * TNCOL;

    __shared__ char sm[40960];
    const int tid = threadIdx.x;
    const int lane = tid & 63, w = tid >> 6;
    const int lr = lane & 15, lq = lane >> 4;
    const int wr0 = (w >> 1) * 32, wc0 = (w & 1) * 16;

    // staging source byte offsets (chunk-invariant; +kc*128 per chunk).
    // list is unsorted & unpadded: clamp to cnt-1 (pad rows duplicate last row).
    int aoff[2], boff[3];
#pragma unroll
    for (int i = 0; i < 2; ++i) {
        int u = i * 256 + tid, r = u >> 3, s = u & 7;
        int rr = row0 + r; if (rr > cnt - 1) rr = cnt - 1;
        aoff[i] = list[rr] * 1024 + ((s ^ (r & 7)) << 4);
    }
#pragma unroll
    for (int j = 0; j < 3; ++j) {
        int u = j * 256 + tid, br = u >> 3, s = u & 7;
        int wr = (br >> 5) * DH + col0 + (br & 31);
        boff[j] = wr * 1024 + ((s ^ (br & 7)) << 4);
    }

    // fragment LDS byte offsets (chunk-invariant)
    int fa[2][2], fb[3][2];
#pragma unroll
    for (int rf = 0; rf < 2; ++rf)
#pragma unroll
        for (int ks = 0; ks < 2; ++ks) {
            int row = wr0 + rf * 16 + lr;
            int sb = ks * 4 + lq;
            fa[rf][ks] = row * 128 + ((sb ^ (row & 7)) << 4);
        }
#pragma unroll
    for (int g = 0; g < 3; ++g)
#pragma unroll
        for (int ks = 0; ks < 2; ++ks) {
            int br = g * 32 + wc0 + lr;
            int sb = ks * 4 + lq;
            fb[g][ks] = br * 128 + ((sb ^ (br & 7)) << 4);
        }

    f4 hh[2][3] = {}, cc[2][3] = {};
    const char* Ah = (const char*)Hch;
    const char* Al = (const char*)Hcl;
    const char* Bh = (const char*)Wh;
    const char* Bl = (const char*)Wl;

    for (int kc = 0; kc < 8; ++kc) {
        const int kb = kc * 128;
#pragma unroll
        for (int i = 0; i < 2; ++i) {
            gl_lds16(Ah + aoff[i] + kb, sm + (i * 256 + tid) * 16);
            gl_lds16(Al + aoff[i] + kb, sm + 8192 + (i * 256 + tid) * 16);
        }
#pragma unroll
        for (int j = 0; j < 3; ++j) {
            gl_lds16(Bh + boff[j] + kb, sm + 16384 + (j * 256 + tid) * 16);
            gl_lds16(Bl + boff[j] + kb, sm + 28672 + (j * 256 + tid) * 16);
        }
        __syncthreads();
#pragma unroll
        for (int ks = 0; ks < 2; ++ks) {
            h8 a0h = *(const h8*)(sm + fa[0][ks]);
            h8 a0l = *(const h8*)(sm + 8192 + fa[0][ks]);
            h8 a1h = *(const h8*)(sm + fa[1][ks]);
            h8 a1l = *(const h8*)(sm + 8192 + fa[1][ks]);
#pragma unroll
            for (int g = 0; g < 3; ++g) {
                h8 bh = *(const h8*)(sm + 16384 + fb[g][ks]);
                h8 bl = *(const h8*)(sm + 28672 + fb[g][ks]);
                hh[0][g] = __builtin_amdgcn_mfma_f32_16x16x32_f16(a0h, bh, hh[0][g], 0, 0, 0);
                cc[0][g] = __builtin_amdgcn_mfma_f32_16x16x32_f16(a0h, bl, cc[0][g], 0, 0, 0);
                cc[0][g] = __builtin_amdgcn_mfma_f32_16x16x32_f16(a0l, bh, cc[0][g], 0, 0, 0);
                hh[1][g] = __builtin_amdgcn_mfma_f32_16x16x32_f16(a1h, bh, hh[1][g], 0, 0, 0);
                cc[1][g] = __builtin_amdgcn_mfma_f32_16x16x32_f16(a1h, bl, cc[1][g], 0, 0, 0);
                cc[1][g] = __builtin_amdgcn_mfma_f32_16x16x32_f16(a1l, bh, cc[1][g], 0, 0, 0);
            }
        }
        __syncthreads();
    }

    const float inv = 1.0f / 2048.0f;
#pragma unroll
    for (int rf = 0; rf < 2; ++rf) {
        f4 pR = hh[rf][0] + cc[rf][0] * inv;
        f4 pZ = hh[rf][1] + cc[rf][1] * inv;
        f4 pN = hh[rf][2] + cc[rf][2] * inv;
        const int gj = col0 + wc0 + lr;
#pragma unroll
        for (int reg = 0; reg < 4; ++reg) {
            int pos = row0 + wr0 + rf * 16 + lq * 4 + reg;
            if (pos > cnt - 1) pos = cnt - 1;
            const int gi = list[pos];
            const double* tr = tab + (size_t)x_prev[gi] * (3 * DH);
            float xr = (float)(tr[gj] + (double)pR[reg] + (double)b_hh0[gj]);
            float xz = (float)(tr[DH + gj] + (double)pZ[reg] + (double)b_hh0[DH + gj]);
            float hn_pre = pN[reg] + b_hh0[2 * DH + gj];
            float r = sigf(xr), z = sigf(xz);
            float g = tanhf((float)(tr[2 * DH + gj] + (double)r * (double)hn_pre));
            size_t o = (size_t)gi * DH + gj;
            float ho = rec2(Hch[o], Hcl[o]);
            float h = (1.0f - z) * g + z * ho;
            half_t oh, ol;
            split2(h, oh, ol);
            Hnh[o] = oh; Hnl[o] = ol;
        }
    }
}

// ---------------------------------------------------------------- layers 1/2: f16x2 emulated-fp32, fused K=1024 (x-half then h-half)
__global__ __launch_bounds__(256, 3) void layer12_mfma(
    const half_t* __restrict__ Xh, const half_t* __restrict__ Xl,
    const half_t* __restrict__ Hch, const half_t* __restrict__ Hcl,
    half_t* __restrict__ Hnh, half_t* __restrict__ Hnl,
    const half_t* __restrict__ Wih_h, const half_t* __restrict__ Wih_l,
    const half_t* __restrict__ Whh_h, const half_t* __restrict__ Whh_l,
    const float* __restrict__ b_ih, const float* __restrict__ b_hh,
    const int* __restrict__ list, const int* __restrict__ count) {
    int rt, ct;
    swizzle_rc(blockIdx.x, rt, ct);
    const int row0 = rt * TMR;
    const int cnt = count[0];
    if (row0 >= cnt) return;
    const int col0 = ct * TNCOL;

    __shared__ char sm[40960];
    const int tid = threadIdx.x;
    const int lane = tid & 63, w = tid >> 6;
    const int lr = lane & 15, lq = lane >> 4;
    const int wr0 = (w >> 1) * 32, wc0 = (w & 1) * 16;

    int aoff[2], boff[3];
#pragma unroll
    for (int i = 0; i < 2; ++i) {
        int u = i * 256 + tid, r = u >> 3, s = u & 7;
        int rr = row0 + r; if (rr > cnt - 1) rr = cnt - 1;
        aoff[i] = list[rr] * 1024 + ((s ^ (r & 7)) << 4);
    }
#pragma unroll
    for (int j = 0; j < 3; ++j) {
        int u = j * 256 + tid, br = u >> 3, s = u & 7;
        int wr = (br >> 5) * DH + col0 + (br & 31);
        boff[j] = wr * 1024 + ((s ^ (br & 7)) << 4);
    }

    int fa[2][2], fb[3][2];
#pragma unroll
    for (int rf = 0; rf < 2; ++rf)
#pragma unroll
        for (int ks = 0; ks < 2; ++ks) {
            int row = wr0 + rf * 16 + lr;
            int sb = ks * 4 + lq;
            fa[rf][ks] = row * 128 + ((sb ^ (row & 7)) << 4);
        }
#pragma unroll
    for (int g = 0; g < 3; ++g)
#pragma unroll
        for (int ks = 0; ks < 2; ++ks) {
            int br = g * 32 + wc0 + lr;
            int sb = ks * 4 + lq;
            fb[g][ks] = br * 128 + ((sb ^ (br & 7)) << 4);
        }

    f4 hh[2][3] = {}, cc[2][3] = {}, niS[2] = {};

    for (int kc = 0; kc < 16; ++kc) {
        const int kb = (kc & 7) * 128;
        const char* As_h = (kc < 8) ? (const char*)Xh : (const char*)Hch;
        const char* As_l = (kc < 8) ? (const char*)Xl : (const char*)Hcl;
        const char* Ws_h = (kc < 8) ? (const char*)Wih_h : (const char*)Whh_h;
        const char* Ws_l = (kc < 8) ? (const char*)Wih_l : (const char*)Whh_l;
#pragma unroll
        for (int i = 0; i < 2; ++i) {
            gl_lds16(As_h + aoff[i] + kb, sm + (i * 256 + tid) * 16);
            gl_lds16(As_l + aoff[i] + kb, sm + 8192 + (i * 256 + tid) * 16);
        }
#pragma unroll
        for (int j = 0; j < 3; ++j) {
            gl_lds16(Ws_h + boff[j] + kb, sm + 16384 + (j * 256 + tid) * 16);
            gl_lds16(Ws_l + boff[j] + kb, sm + 28672 + (j * 256 + tid) * 16);
        }
        __syncthreads();
#pragma unroll
        for (int ks = 0; ks < 2; ++ks) {
            h8 a0h = *(const h8*)(sm + fa[0][ks]);
            h8 a0l = *(const h8*)(sm + 8192 + fa[0][ks]);
            h8 a1h = *(const h8*)(sm + fa[1][ks]);
            h8 a1l = *(const h8*)(sm + 8192 + fa[1][ks]);
#pragma unroll
            for (int g = 0; g < 3; ++g) {
                h8 bh = *(const h8*)(sm + 16384 + fb[g][ks]);
                h8 bl = *(const h8*)(sm + 28672 + fb[g][ks]);
                hh[0][g] = __builtin_amdgcn_mfma_f32_16x16x32_f16(a0h, bh, hh[0][g], 0, 0, 0);
                cc[0][g] = __builtin_amdgcn_mfma_f32_16x16x32_f16(a0h, bl, cc[0][g], 0, 0, 0);
                cc[0][g] = __builtin_amdgcn_mfma_f32_16x16x32_f16(a0l, bh, cc[0][g], 0, 0, 0);
                hh[1][g] = __builtin_amdgcn_mfma_f32_16x16x32_f16(a1h, bh, hh[1][g], 0, 0, 0);
                cc[1][g] = __builtin_amdgcn_mfma_f32_16x16x32_f16(a1h, bl, cc[1][g], 0, 0, 0);
                cc[1][g] = __builtin_amdgcn_mfma_f32_16x16x32_f16(a1l, bh, cc[1][g], 0, 0, 0);
            }
        }
        __syncthreads();
        if (kc == 7) {
            // end of x-half: save i_n partial, reset n-gate accumulators
#pragma unroll
            for (int rf = 0; rf < 2; ++rf) {
                niS[rf] = hh[rf][2] + cc[rf][2] * (1.0f / 2048.0f);
                f4 zz = {0.0f, 0.0f, 0.0f, 0.0f};
                hh[rf][2] = zz;
                cc[rf][2] = zz;
            }
        }
    }

    const float inv = 1.0f / 2048.0f;
#pragma unroll
    for (int rf = 0; rf < 2; ++rf) {
        f4 pR = hh[rf][0] + cc[rf][0] * inv;
        f4 pZ = hh[rf][1] + cc[rf][1] * inv;
        f4 pNH = hh[rf][2] + cc[rf][2] * inv;
        f4 pNI = niS[rf];
        const int gj = col0 + wc0 + lr;
#pragma unroll
        for (int reg = 0; reg < 4; ++reg) {
            int pos = row0 + wr0 + rf * 16 + lq * 4 + reg;
            if (pos > cnt - 1) pos = cnt - 1;
            const int gi = list[pos];
            float xr = pR[reg] + b_ih[gj] + b_hh[gj];
            float xz = pZ[reg] + b_ih[DH + gj] + b_hh[DH + gj];
            float xi = pNI[reg] + b_ih[2 * DH + gj];
            float hn_pre = pNH[reg] + b_hh[2 * DH + gj];
            float r = sigf(xr), z = sigf(xz);
            float g = tanhf(xi + r * hn_pre);
            size_t o = (size_t)gi * DH + gj;
            float ho = rec2(Hch[o], Hcl[o]);
            float h = (1.0f - z) * g + z * ho;
            half_t oh, ol;
            split2(h, oh, ol);
            Hnh[o] = oh; Hnl[o] = ol;
        }
    }
}

// ---------------------------------------------------------------- logits + softmax + argmax + token update + fused compaction
__global__ __launch_bounds__(256) void logits_kernel(const half_t* __restrict__ H2h,
                                                     const half_t* __restrict__ H2l,
                                                     const float* __restrict__ h2v_w,
                                                     const float* __restrict__ h2v_b,
                                                     int* __restrict__ x_prev,
                                                     int* __restrict__ eos,
                                                     int* __restrict__ out,
                                                     const int* __restrict__ list,
                                                     const int* __restrict__ count,
                                                     int* __restrict__ list_next,
                                                     int* __restrict__ count_next,
                                                     int t) {
    const int rowbase = blockIdx.x * 16;
    const int cnt = count[0];
    if (rowbase >= cnt) return;

    __shared__ float Ws[VOCAB][65];
    __shared__ float Hs[16][65];
    __shared__ int sact[16];
    const int tid = threadIdx.x;
    double acc[4] = {0.0, 0.0, 0.0, 0.0};

    for (int k0 = 0; k0 < DH; k0 += 64) {
        __syncthreads();
#pragma unroll
        for (int it = 0; it < 16; ++it) {
            int idx = tid + 256 * it;
            int v = idx >> 6, k = idx & 63;
            Ws[v][k] = h2v_w[(size_t)v * DH + k0 + k];
        }
#pragma unroll
        for (int it = 0; it < 4; ++it) {
            int idx = tid + 256 * it;
            int r = idx >> 6, k = idx & 63;
            int pos = rowbase + r; if (pos > cnt - 1) pos = cnt - 1;
            size_t o = (size_t)list[pos] * DH + k0 + k;
            Hs[r][k] = rec2(H2h[o], H2l[o]);
        }
        __syncthreads();
        const int r = tid >> 4;
        const int vb = (tid & 15) * 4;
#pragma unroll 16
        for (int k = 0; k < 64; ++k) {
            double h = (double)Hs[r][k];
            acc[0] += h * (double)Ws[vb + 0][k];
            acc[1] += h * (double)Ws[vb + 1][k];
            acc[2] += h * (double)Ws[vb + 2][k];
            acc[3] += h * (double)Ws[vb + 3][k];
        }
    }

    const int r = tid >> 4;
    const int vb = (tid & 15) * 4;
    float lf[4];
#pragma unroll
    for (int vv = 0; vv < 4; ++vv) lf[vv] = (float)(acc[vv] + (double)h2v_b[vb + vv]);

    float m = fmaxf(fmaxf(lf[0], lf[1]), fmaxf(lf[2], lf[3]));
#pragma unroll
    for (int off = 1; off < 16; off <<= 1) m = fmaxf(m, __shfl_xor(m, off));
    float e[4];
    float ssum = 0.f;
#pragma unroll
    for (int vv = 0; vv < 4; ++vv) { e[vv] = expf(lf[vv] - m); ssum += e[vv]; }
#pragma unroll
    for (int off = 1; off < 16; off <<= 1) ssum += __shfl_xor(ssum, off);

    float best = e[0] / ssum;
    int bi = vb;
#pragma unroll
    for (int vv = 1; vv < 4; ++vv) {
        float pv = e[vv] / ssum;
        if (pv > best) { best = pv; bi = vb + vv; }
    }
#pragma unroll
    for (int off = 1; off < 16; off <<= 1) {
        float ov = __shfl_xor(best, off);
        int oi = __shfl_xor(bi, off);
        if (ov > best || (ov == best && oi < bi)) { best = ov; bi = oi; }
    }
    if ((tid & 15) == 0) {
        const int pos = rowbase + r;
        const bool valid = pos < cnt;
        const int gi = list[valid ? pos : (cnt - 1)];
        const int ee = eos[gi];
        const int xt = bi;
        if (valid) {
            out[(size_t)gi * TMAX + t] = ee ? 0 : xt;
            if (!ee && xt == EOS_TOK) {
                out[NSEQ * TMAX + gi] = t + 1;
                eos[gi] = 1;
            }
            x_prev[gi] = xt;
        }
        sact[r] = (valid && !ee && xt != EOS_TOK) ? gi : -1;
    }
    __syncthreads();
    if (tid == 0) {
        int loc[16], k = 0;
#pragma unroll
        for (int i = 0; i < 16; ++i) { int v = sact[i]; if (v >= 0) loc[k++] = v; }
        if (k > 0) {
            int b = atomicAdd(count_next, k);
            for (int i = 0; i < k; ++i) list_next[b + i] = loc[i];
        }
    }
}

// ---------------------------------------------------------------- host
extern "C" void kernel_launch(void* const* d_in, const int* in_sizes, int n_in,
                              void* d_out, int out_size, void* d_ws, size_t ws_size,
                              hipStream_t stream) {
    const float* Z        = (const float*)d_in[0];
    const float* emb      = (const float*)d_in[1];
    const float* z2h_w    = (const float*)d_in[2];
    const float* z2h_b    = (const float*)d_in[3];
    const float* w_ih0    = (const float*)d_in[4];
    const float* w_ih_rest= (const float*)d_in[5];   // [2][1536][512]
    const float* w_hh     = (const float*)d_in[6];   // [3][1536][512]
    const float* b_ih     = (const float*)d_in[7];   // [3][1536]
    const float* b_hh     = (const float*)d_in[8];
    const float* h2v_w    = (const float*)d_in[9];
    const float* h2v_b    = (const float*)d_in[10];

    int* out = (int*)d_out;
    char* p = (char*)d_ws;
    const size_t HS = (size_t)NSEQ * DH * sizeof(half_t);   // 8 MiB per split buffer
    half_t* Bh[4]; half_t* Bl[4];
    for (int i = 0; i < 4; ++i) { Bh[i] = (half_t*)p; p += HS; }
    for (int i = 0; i < 4; ++i) { Bl[i] = (half_t*)p; p += HS; }
    double* tab = (double*)p; p += (size_t)VOCAB * 3 * DH * sizeof(double);
    const size_t WH = (size_t)3 * DH * DH;   // elems per weight matrix (1536*512)
    half_t* wih_h = (half_t*)p; p += 2 * WH * sizeof(half_t);
    half_t* wih_l = (half_t*)p; p += 2 * WH * sizeof(half_t);
    half_t* whh_h = (half_t*)p; p += 3 * WH * sizeof(half_t);
    half_t* whh_l = (half_t*)p; p += 3 * WH * sizeof(half_t);
    int* x_prev = (int*)p; p += NSEQ * sizeof(int);
    int* eos    = (int*)p; p += NSEQ * sizeof(int);
    int* lists[2];
    lists[0] = (int*)p; p += NSEQ * sizeof(int);
    lists[1] = (int*)p; p += NSEQ * sizeof(int);
    int* counts = (int*)p; p += 128 * sizeof(int);

    // PAD-fill token region so skipped (post-EOS) rows read as PAD=0.
    hipMemsetAsync(out, 0, (size_t)NSEQ * TMAX * sizeof(int), stream);
    init_kernel<<<NSEQ / 256, 256, 0, stream>>>(x_prev, eos, out, lists[0], counts);
    h0_kernel<<<NSEQ, 256, 0, stream>>>(Z, z2h_w, z2h_b,
                                        Bh[0], Bl[0], Bh[1], Bl[1], Bh[2], Bl[2]);
    gi0_kernel<<<VOCAB, 256, 0, stream>>>(emb, w_ih0, b_ih, tab);
    wsplit_kernel<<<(int)((2 * WH + 255) / 256), 256, 0, stream>>>(w_ih_rest, wih_h, wih_l, (int)(2 * WH));
    wsplit_kernel<<<(int)((3 * WH + 255) / 256), 256, 0, stream>>>(w_hh, whh_h, whh_l, (int)(3 * WH));

    int c0 = 0, c1 = 1, c2 = 2, sp = 3;
    const int lgrid = (NSEQ / TMR) * (DH / TNCOL);   // 128*16 = 2048, 1-D swizzled
    for (int t = 1; t < TMAX; ++t) {
        const int* lcur = lists[(t - 1) & 1];
        const int* ccur = counts + (t - 1);
        layer0_mfma<<<lgrid, 256, 0, stream>>>(Bh[c0], Bl[c0], Bh[sp], Bl[sp],
            whh_h, whh_l, b_hh, tab, x_prev, lcur, ccur);
        layer12_mfma<<<lgrid, 256, 0, stream>>>(Bh[sp], Bl[sp], Bh[c1], Bl[c1], Bh[c0], Bl[c0],
            wih_h, wih_l, whh_h + WH, whh_l + WH, b_ih + 3 * DH, b_hh + 3 * DH, lcur, ccur);
        layer12_mfma<<<lgrid, 256, 0, stream>>>(Bh[c0], Bl[c0], Bh[c2], Bl[c2], Bh[c1], Bl[c1],
            wih_h + WH, wih_l + WH, whh_h + 2 * WH, whh_l + 2 * WH,
            b_ih + 6 * DH, b_hh + 6 * DH, lcur, ccur);
        logits_kernel<<<NSEQ / 16, 256, 0, stream>>>(Bh[c1], Bl[c1], h2v_w, h2v_b,
                                                     x_prev, eos, out, lcur, ccur,
                                                     lists[t & 1], counts + t, t);
        int n0 = sp, n1 = c0, n2 = c1, nsp = c2;
        c0 = n0; c1 = n1; c2 = n2; sp = nsp;
    }
}